// Round 5
// baseline (102.200 us; speedup 1.0000x reference)
//
#include <hip/hip_runtime.h>
#include <math.h>

// ---------------- tunables ----------------
#define SCc     8            // supercells per dim
#define NSC     512          // 8^3
#define SCW     32.0f        // supercell width
#define SLAB    2048         // list capacity per cell (= max N supported by sparse path)
#define LSPLIT  8            // list strips per cell in eval
#define QCUT    22.0f        // drop when d2 > QCUT*lambda_max  (term <= 0.1*e^-11 ~ 1.7e-6)

typedef float v2f __attribute__((ext_vector_type(2)));
static __device__ __forceinline__ v2f s2(float s) { v2f r; r.x = s; r.y = s; return r; }
static __device__ __forceinline__ v2f pkfma(v2f a, v2f b, v2f c) {
    return __builtin_elementwise_fma(a, b, c);
}
static __device__ __forceinline__ float fexp2(float x) {
#if __has_builtin(__builtin_amdgcn_exp2f)
    return __builtin_amdgcn_exp2f(x);
#else
    return exp2f(x);
#endif
}

static __device__ __forceinline__ int scell_of(float x, float y, float z) {
    int cx = min(SCc - 1, max(0, (int)(x * (1.0f / SCW))));
    int cy = min(SCc - 1, max(0, (int)(y * (1.0f / SCW))));
    int cz = min(SCc - 1, max(0, (int)(z * (1.0f / SCW))));
    return (cz << 6) | (cy << 3) | cx;
}

// squared distance from Gaussian center to supercell AABB (points always inside volume)
static __device__ __forceinline__ float cell_d2(int c, float mx, float my, float mz) {
    float lx = (c & 7) * SCW,        hx = lx + SCW;
    float ly = ((c >> 3) & 7) * SCW, hy = ly + SCW;
    float lz = (c >> 6) * SCW,       hz = lz + SCW;
    float dx = fmaxf(fmaxf(lx - mx, mx - hx), 0.0f);
    float dy = fmaxf(fmaxf(ly - my, my - hy), 0.0f);
    float dz = fmaxf(fmaxf(lz - mz, mz - hz), 0.0f);
    return dx * dx + dy * dy + dz * dz;
}

// ---------------- K1: per-Gaussian precompute (+aux) and point histogram ----------------
__global__ __launch_bounds__(256) void k_pre(
    const float* __restrict__ positions,
    const float* __restrict__ log_scales,
    const float* __restrict__ rotations,
    const float* __restrict__ weights,
    const float* __restrict__ points,
    float* __restrict__ params,     // N x 12
    float* __restrict__ aux,        // N x 4: ux,uy,uz,r2
    unsigned* __restrict__ pcnt,    // NSC
    int N, int M, int nPre)
{
    if ((int)blockIdx.x < nPre) {
        int i = blockIdx.x * 256 + threadIdx.x;
        if (i >= N) return;

        float s0 = expf(log_scales[3*i+0]);
        float s1 = expf(log_scales[3*i+1]);
        float s2_ = expf(log_scales[3*i+2]);
        float v0 = s0*s0, v1 = s1*s1, v2 = s2_*s2_;

        float qw = rotations[4*i+0], qx = rotations[4*i+1];
        float qy = rotations[4*i+2], qz = rotations[4*i+3];
        float nrm = sqrtf(qw*qw + qx*qx + qy*qy + qz*qz) + 1e-8f;
        float inv = 1.0f / nrm;
        qw *= inv; qx *= inv; qy *= inv; qz *= inv;

        float r00 = 1.f - 2.f*(qy*qy + qz*qz);
        float r01 = 2.f*(qx*qy - qz*qw);
        float r02 = 2.f*(qx*qz + qy*qw);
        float r10 = 2.f*(qx*qy + qz*qw);
        float r11 = 1.f - 2.f*(qx*qx + qz*qz);
        float r12 = 2.f*(qy*qz - qx*qw);
        float r20 = 2.f*(qx*qz - qy*qw);
        float r21 = 2.f*(qy*qz + qx*qw);
        float r22 = 1.f - 2.f*(qx*qx + qy*qy);

        float a = r00*r00*v0 + r01*r01*v1 + r02*r02*v2 + 1e-6f;
        float b = r00*r10*v0 + r01*r11*v1 + r02*r12*v2;
        float c = r00*r20*v0 + r01*r21*v1 + r02*r22*v2;
        float d = r10*r10*v0 + r11*r11*v1 + r12*r12*v2 + 1e-6f;
        float e = r10*r20*v0 + r11*r21*v1 + r12*r22*v2;
        float f = r20*r20*v0 + r21*r21*v1 + r22*r22*v2 + 1e-6f;

        float m00 = d*f - e*e;
        float m01 = c*e - b*f;
        float m02 = b*e - c*d;
        float det = a*m00 + b*m01 + c*m02;
        float id  = 1.0f / det;
        float A00 = m00*id, A01 = m01*id, A02 = m02*id;
        float A11 = (a*f - c*c)*id;
        float A12 = (c*b - a*e)*id;
        float A22 = (a*d - b*b)*id;

        float ux = positions[3*i+0], uy = positions[3*i+1], uz = positions[3*i+2];
        float bx = A00*ux + A01*uy + A02*uz;
        float by = A01*ux + A11*uy + A12*uz;
        float bz = A02*ux + A12*uy + A22*uz;
        float cq = ux*bx + uy*by + uz*bz;

        const float kk = -0.72134752044448170368f; // -0.5 * log2(e)
        float* P = params + 12*i;
        P[0]  = kk*A00;      P[1]  = kk*A11;      P[2]  = kk*A22;      P[3] = 2.f*kk*A01;
        P[4]  = 2.f*kk*A02;  P[5]  = 2.f*kk*A12;  P[6]  = -2.f*kk*bx;  P[7] = -2.f*kk*by;
        P[8]  = -2.f*kk*bz;  P[9]  = kk*cq;       P[10] = weights[i];  P[11] = 0.f;

        // Gershgorin bound on lambda_max(cov) -> cull radius^2
        float L = fmaxf(fmaxf(a + fabsf(b) + fabsf(c),
                              fabsf(b) + d + fabsf(e)),
                        fabsf(c) + fabsf(e) + f);
        aux[4*i+0] = ux; aux[4*i+1] = uy; aux[4*i+2] = uz; aux[4*i+3] = QCUT * L;
    } else {
        int m = ((int)blockIdx.x - nPre) * 256 + threadIdx.x;
        if (m >= M) return;
        int c = scell_of(points[3*m+0], points[3*m+1], points[3*m+2]);
        atomicAdd(&pcnt[c], 1u);
    }
}

// ---------------- K2: blocks 0..NSC-1 build per-cell lists (ballot-ordered,
// deterministic); block NSC scans pcnt -> pstart ----------------
__global__ __launch_bounds__(256) void k_lists(
    const float4* __restrict__ aux4,
    const unsigned* __restrict__ pcnt, unsigned* __restrict__ pstart,
    unsigned* __restrict__ lcnt, unsigned* __restrict__ lists, int N)
{
    if (blockIdx.x == NSC) {  // exclusive scan of pcnt[512] by 256 threads
        __shared__ unsigned sh[256];
        int t = threadIdx.x;
        unsigned a = pcnt[2*t], b = pcnt[2*t+1];
        unsigned s = a + b;
        sh[t] = s;
        __syncthreads();
        for (int d = 1; d < 256; d <<= 1) {
            unsigned add = (t >= d) ? sh[t - d] : 0u;
            __syncthreads();
            sh[t] += add;
            __syncthreads();
        }
        unsigned ex = sh[t] - s;
        pstart[2*t] = ex; pstart[2*t+1] = ex + a;
        return;
    }
    int c    = blockIdx.x;
    int lane = threadIdx.x & 63;
    int w    = threadIdx.x >> 6;            // 4 waves, each owns a 512-chunk of N
    unsigned long long lt = (1ULL << lane) - 1ULL;
    int gbase = w * 512;
    int nIter = 8;                          // 512/64

    unsigned cnt = 0;
    for (int it = 0; it < nIter; ++it) {
        int g = gbase + it*64 + lane;
        bool keep = false;
        if (g < N) { float4 a = aux4[g]; keep = cell_d2(c, a.x, a.y, a.z) <= a.w; }
        cnt += (unsigned)__popcll(__ballot(keep));
    }
    __shared__ unsigned wc[4];
    if (lane == 0) wc[w] = cnt;
    __syncthreads();
    unsigned pos = 0;
#pragma unroll
    for (int i = 0; i < 4; ++i) pos += (i < w) ? wc[i] : 0u;
    unsigned total = wc[0] + wc[1] + wc[2] + wc[3];
    unsigned* slab = lists + (size_t)c * SLAB;
    for (int it = 0; it < nIter; ++it) {
        int g = gbase + it*64 + lane;
        bool keep = false;
        if (g < N) { float4 a = aux4[g]; keep = cell_d2(c, a.x, a.y, a.z) <= a.w; }
        unsigned long long mask = __ballot(keep);
        if (keep) slab[pos + (unsigned)__popcll(mask & lt)] = (unsigned)g;
        pos += (unsigned)__popcll(mask);
    }
    if (threadIdx.x == 0) lcnt[c] = total;
}

// ---------------- K3: gather points into per-cell contiguous float4 (xyz, idx) ----------------
__global__ __launch_bounds__(256) void k_scatter(
    const float* __restrict__ points, const unsigned* __restrict__ pstart,
    unsigned* __restrict__ pfill, float4* __restrict__ sortedPts, int M)
{
    int m = blockIdx.x * 256 + threadIdx.x;
    if (m >= M) return;
    float x = points[3*m+0], y = points[3*m+1], z = points[3*m+2];
    int c = scell_of(x, y, z);
    unsigned r = atomicAdd(&pfill[c], 1u);
    float4 sp; sp.x = x; sp.y = y; sp.z = z; sp.w = __uint_as_float((unsigned)m);
    sortedPts[pstart[c] + r] = sp;
}

// ---------------- K4: eval — one wave per (cell, list-strip), 128 pts packed ----------------
__global__ __launch_bounds__(64) void k_eval(
    const float4* __restrict__ sortedPts, const float4* __restrict__ P4,
    const unsigned* __restrict__ pcnt, const unsigned* __restrict__ pstart,
    const unsigned* __restrict__ lcnt, const unsigned* __restrict__ lists,
    float* __restrict__ out)
{
    int c    = blockIdx.x;
    int lane = threadIdx.x;
    int npts = (int)pcnt[c];
    unsigned ps = pstart[c];
    int len  = (int)lcnt[c];
    int k0 = (len * (int)blockIdx.y) / LSPLIT;
    int k1 = (len * ((int)blockIdx.y + 1)) / LSPLIT;
    const unsigned* lst = lists + (size_t)c * SLAB;

    for (int pb = 0; pb < npts; pb += 128) {
        int i0 = pb + lane, i1 = i0 + 64;
        bool a0 = i0 < npts, a1 = i1 < npts;
        float4 p0 = sortedPts[ps + (a0 ? i0 : 0)];
        float4 p1 = sortedPts[ps + (a1 ? i1 : 0)];
        v2f X, Y, Z;
        X.x = p0.x; X.y = p1.x;
        Y.x = p0.y; Y.y = p1.y;
        Z.x = p0.z; Z.y = p1.z;
        v2f XX = X*X, YY = Y*Y, ZZ = Z*Z;
        v2f XY = X*Y, XZ = X*Z, YZ = Y*Z;
        v2f acc; acc.x = 0.f; acc.y = 0.f;

#pragma unroll 2
        for (int k = k0; k < k1; ++k) {
            int g = (int)lst[k];                 // wave-uniform -> scalar loads
            float4 q0 = P4[3*g + 0];             // Q00,Q11,Q22,Q01
            float4 q1 = P4[3*g + 1];             // Q02,Q12,Lx,Ly
            float4 q2 = P4[3*g + 2];             // Lz,C,W,pad

            v2f t0 = pkfma(s2(q0.x), XX, s2(q2.y));
            t0 = pkfma(s2(q0.w), XY, t0);
            t0 = pkfma(s2(q1.z), X,  t0);
            v2f t1 = s2(q0.y) * YY;
            t1 = pkfma(s2(q1.y), YZ, t1);
            t1 = pkfma(s2(q1.w), Y,  t1);
            v2f t2 = s2(q0.z) * ZZ;
            t2 = pkfma(s2(q1.x), XZ, t2);
            t2 = pkfma(s2(q2.x), Z,  t2);
            v2f e2 = (t0 + t1) + t2;
            v2f gg; gg.x = fexp2(e2.x); gg.y = fexp2(e2.y);
            acc = pkfma(s2(q2.z), gg, acc);
        }
        if (a0) atomicAdd(&out[__float_as_uint(p0.w)], acc.x);
        if (a1) atomicAdd(&out[__float_as_uint(p1.w)], acc.y);
    }
}

// ---------------- dense fallback (R3 kernel) ----------------
#define NSPLIT 32
#define COARSEN 4
__global__ __launch_bounds__(256, 8) void gbf_eval_dense(
    const float* __restrict__ points,
    const float4* __restrict__ params,
    float* __restrict__ out, int M, int N, int nPer)
{
    int p0 = blockIdx.x * (256 * COARSEN) + threadIdx.x;
    int p1 = p0 + 256, p2 = p0 + 512, p3 = p0 + 768;
    int c0 = min(p0, M-1), c1 = min(p1, M-1), c2 = min(p2, M-1), c3 = min(p3, M-1);

    v2f X1, Y1, Z1, X2_, Y2_, Z2_;
    X1.x = points[3*c0+0]; X1.y = points[3*c1+0];
    Y1.x = points[3*c0+1]; Y1.y = points[3*c1+1];
    Z1.x = points[3*c0+2]; Z1.y = points[3*c1+2];
    X2_.x = points[3*c2+0]; X2_.y = points[3*c3+0];
    Y2_.x = points[3*c2+1]; Y2_.y = points[3*c3+1];
    Z2_.x = points[3*c2+2]; Z2_.y = points[3*c3+2];

    v2f XX1 = X1*X1, YY1 = Y1*Y1, ZZ1 = Z1*Z1;
    v2f XY1 = X1*Y1, XZ1 = X1*Z1, YZ1 = Y1*Z1;
    v2f XX2 = X2_*X2_, YY2 = Y2_*Y2_, ZZ2 = Z2_*Z2_;
    v2f XY2 = X2_*Y2_, XZ2 = X2_*Z2_, YZ2 = Y2_*Z2_;

    int jbase = blockIdx.y * nPer;
    int jend = min(nPer, N - jbase);
    int base = jbase * 3;
    v2f acc1; acc1.x = 0.f; acc1.y = 0.f;
    v2f acc2 = acc1;

#pragma unroll 2
    for (int j = 0; j < jend; ++j) {
        float4 q0 = params[base + 3*j + 0];
        float4 q1 = params[base + 3*j + 1];
        float4 q2 = params[base + 3*j + 2];

        v2f t0 = pkfma(s2(q0.x), XX1, s2(q2.y));
        t0 = pkfma(s2(q0.w), XY1, t0);
        t0 = pkfma(s2(q1.z), X1,  t0);
        v2f t1 = s2(q0.y) * YY1;
        t1 = pkfma(s2(q1.y), YZ1, t1);
        t1 = pkfma(s2(q1.w), Y1,  t1);
        v2f t2 = s2(q0.z) * ZZ1;
        t2 = pkfma(s2(q1.x), XZ1, t2);
        t2 = pkfma(s2(q2.x), Z1,  t2);
        v2f e1 = (t0 + t1) + t2;

        v2f u0 = pkfma(s2(q0.x), XX2, s2(q2.y));
        u0 = pkfma(s2(q0.w), XY2, u0);
        u0 = pkfma(s2(q1.z), X2_, u0);
        v2f u1 = s2(q0.y) * YY2;
        u1 = pkfma(s2(q1.y), YZ2, u1);
        u1 = pkfma(s2(q1.w), Y2_, u1);
        v2f u2 = s2(q0.z) * ZZ2;
        u2 = pkfma(s2(q1.x), XZ2, u2);
        u2 = pkfma(s2(q2.x), Z2_, u2);
        v2f e2 = (u0 + u1) + u2;

        v2f g1, g2;
        g1.x = fexp2(e1.x); g1.y = fexp2(e1.y);
        g2.x = fexp2(e2.x); g2.y = fexp2(e2.y);
        acc1 = pkfma(s2(q2.z), g1, acc1);
        acc2 = pkfma(s2(q2.z), g2, acc2);
    }
    if (p0 < M) atomicAdd(&out[p0], acc1.x);
    if (p1 < M) atomicAdd(&out[p1], acc1.y);
    if (p2 < M) atomicAdd(&out[p2], acc2.x);
    if (p3 < M) atomicAdd(&out[p3], acc2.y);
}

// ---------------- host ----------------
extern "C" void kernel_launch(void* const* d_in, const int* in_sizes, int n_in,
                              void* d_out, int out_size, void* d_ws, size_t ws_size,
                              hipStream_t stream)
{
    const float* points     = (const float*)d_in[0];
    const float* positions  = (const float*)d_in[1];
    const float* log_scales = (const float*)d_in[2];
    const float* rotations  = (const float*)d_in[3];
    const float* weights    = (const float*)d_in[4];
    int M = in_sizes[0] / 3;
    int N = in_sizes[4];
    float* out = (float*)d_out;

    // workspace layout
    char* w = (char*)d_ws;
    size_t o = 0;
    float*    params   = (float*)(w + o);    o += (size_t)N * 12 * 4;
    float*    aux      = (float*)(w + o);    o += (size_t)N * 4 * 4;
    unsigned* pcnt     = (unsigned*)(w + o); o += NSC * 4;
    unsigned* pfill    = (unsigned*)(w + o); o += NSC * 4;
    unsigned* pstart   = (unsigned*)(w + o); o += NSC * 4;
    unsigned* lcnt     = (unsigned*)(w + o); o += NSC * 4;
    unsigned* lists    = (unsigned*)(w + o); o += (size_t)NSC * SLAB * 4;
    float4*   sortedPts= (float4*)(w + o);   o += (size_t)M * 16;

    int nPre  = (N + 255) / 256;
    int nHist = (M + 255) / 256;

    hipMemsetAsync(d_out, 0, (size_t)out_size * sizeof(float), stream);

    if (ws_size < o || N > SLAB) {
        // dense fallback (precompute only, then R3 kernel)
        k_pre<<<dim3(nPre), dim3(256), 0, stream>>>(
            positions, log_scales, rotations, weights, points,
            params, aux, pcnt, N, M, nPre);
        int nPer = (N + NSPLIT - 1) / NSPLIT;
        dim3 grid((M + 256 * COARSEN - 1) / (256 * COARSEN), NSPLIT);
        gbf_eval_dense<<<grid, dim3(256), 0, stream>>>(points, (const float4*)params, out, M, N, nPer);
        return;
    }

    hipMemsetAsync(pcnt, 0, NSC * 2 * 4, stream);   // pcnt + pfill

    k_pre<<<dim3(nPre + nHist), dim3(256), 0, stream>>>(
        positions, log_scales, rotations, weights, points,
        params, aux, pcnt, N, M, nPre);

    k_lists<<<dim3(NSC + 1), dim3(256), 0, stream>>>(
        (const float4*)aux, pcnt, pstart, lcnt, lists, N);

    k_scatter<<<dim3(nHist), dim3(256), 0, stream>>>(
        points, pstart, pfill, sortedPts, M);

    k_eval<<<dim3(NSC, LSPLIT), dim3(64), 0, stream>>>(
        sortedPts, (const float4*)params, pcnt, pstart, lcnt, lists, out);
}

// Round 6
// 42.932 us; speedup vs baseline: 2.3805x; 2.3805x over previous
//
#include <hip/hip_runtime.h>
#include <math.h>

// ---------------- tunables ----------------
#define SCc     8            // supercells per dim
#define NSC     512          // 8^3
#define SCW     32.0f        // supercell width
#define SLAB    2048         // Gaussian-list capacity per cell (= max N for sparse path)
#define LLEN    512          // staged list chunk (LDS = LLEN*48B = 24 KB)
#define EVB     128          // eval block threads
#define ECH     2            // point-chunk blocks per cell
#define NHB     32           // histogram blocks
#define QCUT    22.0f        // drop when d2 > QCUT*lambda_max (term <= 0.1*e^-11)

typedef float v2f __attribute__((ext_vector_type(2)));
static __device__ __forceinline__ v2f s2(float s) { v2f r; r.x = s; r.y = s; return r; }
static __device__ __forceinline__ v2f pkfma(v2f a, v2f b, v2f c) {
    return __builtin_elementwise_fma(a, b, c);
}
static __device__ __forceinline__ float fexp2(float x) {
#if __has_builtin(__builtin_amdgcn_exp2f)
    return __builtin_amdgcn_exp2f(x);
#else
    return exp2f(x);
#endif
}

static __device__ __forceinline__ int scell_of(float x, float y, float z) {
    int cx = min(SCc - 1, max(0, (int)(x * (1.0f / SCW))));
    int cy = min(SCc - 1, max(0, (int)(y * (1.0f / SCW))));
    int cz = min(SCc - 1, max(0, (int)(z * (1.0f / SCW))));
    return (cz << 6) | (cy << 3) | cx;
}

static __device__ __forceinline__ float cell_d2(int c, float mx, float my, float mz) {
    float lx = (c & 7) * SCW,        hx = lx + SCW;
    float ly = ((c >> 3) & 7) * SCW, hy = ly + SCW;
    float lz = (c >> 6) * SCW,       hz = lz + SCW;
    float dx = fmaxf(fmaxf(lx - mx, mx - hx), 0.0f);
    float dy = fmaxf(fmaxf(ly - my, my - hy), 0.0f);
    float dz = fmaxf(fmaxf(lz - mz, mz - hz), 0.0f);
    return dx * dx + dy * dy + dz * dz;
}

// ---------------- K1: per-Gaussian precompute; LDS point histogram ----------------
__global__ __launch_bounds__(256) void k_pre(
    const float* __restrict__ positions,
    const float* __restrict__ log_scales,
    const float* __restrict__ rotations,
    const float* __restrict__ weights,
    const float* __restrict__ points,
    float* __restrict__ params,     // N x 12
    float* __restrict__ aux,        // N x 4: ux,uy,uz,r2
    unsigned* __restrict__ pcnt,    // NSC
    int N, int M, int nPre)
{
    if ((int)blockIdx.x < nPre) {
        int i = blockIdx.x * 256 + threadIdx.x;
        if (i >= N) return;

        float s0 = expf(log_scales[3*i+0]);
        float s1 = expf(log_scales[3*i+1]);
        float s2_ = expf(log_scales[3*i+2]);
        float v0 = s0*s0, v1 = s1*s1, v2 = s2_*s2_;

        float qw = rotations[4*i+0], qx = rotations[4*i+1];
        float qy = rotations[4*i+2], qz = rotations[4*i+3];
        float nrm = sqrtf(qw*qw + qx*qx + qy*qy + qz*qz) + 1e-8f;
        float inv = 1.0f / nrm;
        qw *= inv; qx *= inv; qy *= inv; qz *= inv;

        float r00 = 1.f - 2.f*(qy*qy + qz*qz);
        float r01 = 2.f*(qx*qy - qz*qw);
        float r02 = 2.f*(qx*qz + qy*qw);
        float r10 = 2.f*(qx*qy + qz*qw);
        float r11 = 1.f - 2.f*(qx*qx + qz*qz);
        float r12 = 2.f*(qy*qz - qx*qw);
        float r20 = 2.f*(qx*qz - qy*qw);
        float r21 = 2.f*(qy*qz + qx*qw);
        float r22 = 1.f - 2.f*(qx*qx + qy*qy);

        float a = r00*r00*v0 + r01*r01*v1 + r02*r02*v2 + 1e-6f;
        float b = r00*r10*v0 + r01*r11*v1 + r02*r12*v2;
        float c = r00*r20*v0 + r01*r21*v1 + r02*r22*v2;
        float d = r10*r10*v0 + r11*r11*v1 + r12*r12*v2 + 1e-6f;
        float e = r10*r20*v0 + r11*r21*v1 + r12*r22*v2;
        float f = r20*r20*v0 + r21*r21*v1 + r22*r22*v2 + 1e-6f;

        float m00 = d*f - e*e;
        float m01 = c*e - b*f;
        float m02 = b*e - c*d;
        float det = a*m00 + b*m01 + c*m02;
        float id  = 1.0f / det;
        float A00 = m00*id, A01 = m01*id, A02 = m02*id;
        float A11 = (a*f - c*c)*id;
        float A12 = (c*b - a*e)*id;
        float A22 = (a*d - b*b)*id;

        float ux = positions[3*i+0], uy = positions[3*i+1], uz = positions[3*i+2];
        float bx = A00*ux + A01*uy + A02*uz;
        float by = A01*ux + A11*uy + A12*uz;
        float bz = A02*ux + A12*uy + A22*uz;
        float cq = ux*bx + uy*by + uz*bz;

        const float kk = -0.72134752044448170368f; // -0.5 * log2(e)
        float* P = params + 12*i;
        P[0]  = kk*A00;      P[1]  = kk*A11;      P[2]  = kk*A22;      P[3] = 2.f*kk*A01;
        P[4]  = 2.f*kk*A02;  P[5]  = 2.f*kk*A12;  P[6]  = -2.f*kk*bx;  P[7] = -2.f*kk*by;
        P[8]  = -2.f*kk*bz;  P[9]  = kk*cq;       P[10] = weights[i];  P[11] = 0.f;

        float L = fmaxf(fmaxf(a + fabsf(b) + fabsf(c),
                              fabsf(b) + d + fabsf(e)),
                        fabsf(c) + fabsf(e) + f);
        aux[4*i+0] = ux; aux[4*i+1] = uy; aux[4*i+2] = uz; aux[4*i+3] = QCUT * L;
    } else {
        __shared__ unsigned hist[NSC];
        int tid = threadIdx.x;
        for (int b = tid; b < NSC; b += 256) hist[b] = 0u;
        __syncthreads();
        int h = (int)blockIdx.x - nPre;
        int mh = (M + NHB - 1) / NHB;
        int m0 = h * mh, m1 = min(M, m0 + mh);
        for (int m = m0 + tid; m < m1; m += 256) {
            int c = scell_of(points[3*m+0], points[3*m+1], points[3*m+2]);
            atomicAdd(&hist[c], 1u);
        }
        __syncthreads();
        for (int b = tid; b < NSC; b += 256) {
            unsigned v = hist[b];
            if (v) atomicAdd(&pcnt[b], v);
        }
    }
}

// ---------------- K2: blocks 0..NSC-1 build per-cell Gaussian lists (ballot-ordered,
// deterministic); block NSC scans pcnt -> pstart ----------------
__global__ __launch_bounds__(256) void k_lists(
    const float4* __restrict__ aux4,
    const unsigned* __restrict__ pcnt, unsigned* __restrict__ pstart,
    unsigned* __restrict__ lcnt, unsigned* __restrict__ lists, int N)
{
    if (blockIdx.x == NSC) {  // exclusive scan of pcnt[512] by 256 threads
        __shared__ unsigned sh[256];
        int t = threadIdx.x;
        unsigned a = pcnt[2*t], b = pcnt[2*t+1];
        unsigned s = a + b;
        sh[t] = s;
        __syncthreads();
        for (int d = 1; d < 256; d <<= 1) {
            unsigned add = (t >= d) ? sh[t - d] : 0u;
            __syncthreads();
            sh[t] += add;
            __syncthreads();
        }
        unsigned ex = sh[t] - s;
        pstart[2*t] = ex; pstart[2*t+1] = ex + a;
        return;
    }
    int c    = blockIdx.x;
    int lane = threadIdx.x & 63;
    int w    = threadIdx.x >> 6;            // 4 waves, each owns a 512-chunk of N
    unsigned long long lt = (1ULL << lane) - 1ULL;
    int gbase = w * 512;

    unsigned cnt = 0;
    for (int it = 0; it < 8; ++it) {
        int g = gbase + it*64 + lane;
        bool keep = false;
        if (g < N) { float4 a = aux4[g]; keep = cell_d2(c, a.x, a.y, a.z) <= a.w; }
        cnt += (unsigned)__popcll(__ballot(keep));
    }
    __shared__ unsigned wc[4];
    if (lane == 0) wc[w] = cnt;
    __syncthreads();
    unsigned pos = 0;
#pragma unroll
    for (int i = 0; i < 4; ++i) pos += (i < w) ? wc[i] : 0u;
    unsigned total = wc[0] + wc[1] + wc[2] + wc[3];
    unsigned* slab = lists + (size_t)c * SLAB;
    for (int it = 0; it < 8; ++it) {
        int g = gbase + it*64 + lane;
        bool keep = false;
        if (g < N) { float4 a = aux4[g]; keep = cell_d2(c, a.x, a.y, a.z) <= a.w; }
        unsigned long long mask = __ballot(keep);
        if (keep) slab[pos + (unsigned)__popcll(mask & lt)] = (unsigned)g;
        pos += (unsigned)__popcll(mask);
    }
    if (threadIdx.x == 0) lcnt[c] = total;
}

// ---------------- K3: LDS-aggregated scatter of points into per-cell ranges ----------------
__global__ __launch_bounds__(256) void k_scatter(
    const float* __restrict__ points, const unsigned* __restrict__ pstart,
    unsigned* __restrict__ pfill, float4* __restrict__ sortedPts, int M)
{
    __shared__ unsigned cnt[NSC];
    __shared__ unsigned base[NSC];
    int tid = threadIdx.x;
    for (int b = tid; b < NSC; b += 256) cnt[b] = 0u;
    __syncthreads();
    int m = blockIdx.x * 256 + tid;
    int c = 0; unsigned r = 0; float x=0,y=0,z=0;
    bool act = m < M;
    if (act) {
        x = points[3*m+0]; y = points[3*m+1]; z = points[3*m+2];
        c = scell_of(x, y, z);
        r = atomicAdd(&cnt[c], 1u);
    }
    __syncthreads();
    for (int b = tid; b < NSC; b += 256) {
        unsigned v = cnt[b];
        if (v) base[b] = atomicAdd(&pfill[b], v);
    }
    __syncthreads();
    if (act) {
        float4 sp; sp.x = x; sp.y = y; sp.z = z; sp.w = __uint_as_float((unsigned)m);
        sortedPts[pstart[c] + base[c] + r] = sp;
    }
}

// ---------------- K4: eval — LDS-staged list, atomic-free output ----------------
__global__ __launch_bounds__(EVB) void k_eval(
    const float4* __restrict__ sortedPts, const float4* __restrict__ P4,
    const unsigned* __restrict__ pcnt, const unsigned* __restrict__ pstart,
    const unsigned* __restrict__ lcnt, const unsigned* __restrict__ lists,
    float* __restrict__ out)
{
    __shared__ float4 sl[LLEN * 3];
    int c    = blockIdx.x;
    int tid  = threadIdx.x;
    int npts = (int)pcnt[c];
    unsigned ps = pstart[c];
    int len  = (int)lcnt[c];
    const unsigned* lst = lists + (size_t)c * SLAB;

    for (int pb = (int)blockIdx.y * EVB; pb < npts; pb += ECH * EVB) {
        int pi = pb + tid;
        bool act = pi < npts;
        float4 p = sortedPts[ps + (act ? pi : 0)];
        float x = p.x, yv = p.y, zv = p.z;
        float xx = x*x, yy = yv*yv, zz = zv*zv;
        float xy = x*yv, xz = x*zv, yz = yv*zv;
        float acc = 0.f;

        for (int k0 = 0; k0 < len; k0 += LLEN) {
            int kn = min(LLEN, len - k0);
            __syncthreads();
            for (int e = tid; e < kn; e += EVB) {
                int g = (int)lst[k0 + e];
                sl[3*e + 0] = P4[3*g + 0];
                sl[3*e + 1] = P4[3*g + 1];
                sl[3*e + 2] = P4[3*g + 2];
            }
            __syncthreads();
#pragma unroll 2
            for (int e = 0; e < kn; ++e) {
                float4 q0 = sl[3*e + 0];   // Q00,Q11,Q22,Q01
                float4 q1 = sl[3*e + 1];   // Q02,Q12,Lx,Ly
                float4 q2 = sl[3*e + 2];   // Lz,C,W,pad

                float t0 = fmaf(q0.x, xx, q2.y);
                t0 = fmaf(q0.w, xy, t0);
                t0 = fmaf(q1.z, x,  t0);
                float t1 = q0.y * yy;
                t1 = fmaf(q1.y, yz, t1);
                t1 = fmaf(q1.w, yv, t1);
                float t2 = q0.z * zz;
                t2 = fmaf(q1.x, xz, t2);
                t2 = fmaf(q2.x, zv, t2);
                float e2 = (t0 + t1) + t2;
                acc = fmaf(q2.z, fexp2(e2), acc);
            }
        }
        if (act) out[__float_as_uint(p.w)] = acc;   // written exactly once, no atomic
    }
}

// ---------------- dense fallback (R3 kernel) ----------------
#define NSPLIT 32
#define COARSEN 4
__global__ __launch_bounds__(256, 8) void gbf_eval_dense(
    const float* __restrict__ points,
    const float4* __restrict__ params,
    float* __restrict__ out, int M, int N, int nPer)
{
    int p0 = blockIdx.x * (256 * COARSEN) + threadIdx.x;
    int p1 = p0 + 256, p2 = p0 + 512, p3 = p0 + 768;
    int c0 = min(p0, M-1), c1 = min(p1, M-1), c2 = min(p2, M-1), c3 = min(p3, M-1);

    v2f X1, Y1, Z1, X2_, Y2_, Z2_;
    X1.x = points[3*c0+0]; X1.y = points[3*c1+0];
    Y1.x = points[3*c0+1]; Y1.y = points[3*c1+1];
    Z1.x = points[3*c0+2]; Z1.y = points[3*c1+2];
    X2_.x = points[3*c2+0]; X2_.y = points[3*c3+0];
    Y2_.x = points[3*c2+1]; Y2_.y = points[3*c3+1];
    Z2_.x = points[3*c2+2]; Z2_.y = points[3*c3+2];

    v2f XX1 = X1*X1, YY1 = Y1*Y1, ZZ1 = Z1*Z1;
    v2f XY1 = X1*Y1, XZ1 = X1*Z1, YZ1 = Y1*Z1;
    v2f XX2 = X2_*X2_, YY2 = Y2_*Y2_, ZZ2 = Z2_*Z2_;
    v2f XY2 = X2_*Y2_, XZ2 = X2_*Z2_, YZ2 = Y2_*Z2_;

    int jbase = blockIdx.y * nPer;
    int jend = min(nPer, N - jbase);
    int base = jbase * 3;
    v2f acc1; acc1.x = 0.f; acc1.y = 0.f;
    v2f acc2 = acc1;

#pragma unroll 2
    for (int j = 0; j < jend; ++j) {
        float4 q0 = params[base + 3*j + 0];
        float4 q1 = params[base + 3*j + 1];
        float4 q2 = params[base + 3*j + 2];

        v2f t0 = pkfma(s2(q0.x), XX1, s2(q2.y));
        t0 = pkfma(s2(q0.w), XY1, t0);
        t0 = pkfma(s2(q1.z), X1,  t0);
        v2f t1 = s2(q0.y) * YY1;
        t1 = pkfma(s2(q1.y), YZ1, t1);
        t1 = pkfma(s2(q1.w), Y1,  t1);
        v2f t2 = s2(q0.z) * ZZ1;
        t2 = pkfma(s2(q1.x), XZ1, t2);
        t2 = pkfma(s2(q2.x), Z1,  t2);
        v2f e1 = (t0 + t1) + t2;

        v2f u0 = pkfma(s2(q0.x), XX2, s2(q2.y));
        u0 = pkfma(s2(q0.w), XY2, u0);
        u0 = pkfma(s2(q1.z), X2_, u0);
        v2f u1 = s2(q0.y) * YY2;
        u1 = pkfma(s2(q1.y), YZ2, u1);
        u1 = pkfma(s2(q1.w), Y2_, u1);
        v2f u2 = s2(q0.z) * ZZ2;
        u2 = pkfma(s2(q1.x), XZ2, u2);
        u2 = pkfma(s2(q2.x), Z2_, u2);
        v2f e2 = (u0 + u1) + u2;

        v2f g1, g2;
        g1.x = fexp2(e1.x); g1.y = fexp2(e1.y);
        g2.x = fexp2(e2.x); g2.y = fexp2(e2.y);
        acc1 = pkfma(s2(q2.z), g1, acc1);
        acc2 = pkfma(s2(q2.z), g2, acc2);
    }
    if (p0 < M) atomicAdd(&out[p0], acc1.x);
    if (p1 < M) atomicAdd(&out[p1], acc1.y);
    if (p2 < M) atomicAdd(&out[p2], acc2.x);
    if (p3 < M) atomicAdd(&out[p3], acc2.y);
}

// ---------------- host ----------------
extern "C" void kernel_launch(void* const* d_in, const int* in_sizes, int n_in,
                              void* d_out, int out_size, void* d_ws, size_t ws_size,
                              hipStream_t stream)
{
    const float* points     = (const float*)d_in[0];
    const float* positions  = (const float*)d_in[1];
    const float* log_scales = (const float*)d_in[2];
    const float* rotations  = (const float*)d_in[3];
    const float* weights    = (const float*)d_in[4];
    int M = in_sizes[0] / 3;
    int N = in_sizes[4];
    float* out = (float*)d_out;

    // workspace layout
    char* w = (char*)d_ws;
    size_t o = 0;
    float*    params   = (float*)(w + o);    o += (size_t)N * 12 * 4;
    float*    aux      = (float*)(w + o);    o += (size_t)N * 4 * 4;
    unsigned* pcnt     = (unsigned*)(w + o); o += NSC * 4;
    unsigned* pfill    = (unsigned*)(w + o); o += NSC * 4;
    unsigned* pstart   = (unsigned*)(w + o); o += NSC * 4;
    unsigned* lcnt     = (unsigned*)(w + o); o += NSC * 4;
    unsigned* lists    = (unsigned*)(w + o); o += (size_t)NSC * SLAB * 4;
    float4*   sortedPts= (float4*)(w + o);   o += (size_t)M * 16;

    int nPre  = (N + 255) / 256;
    int nHist = (M + 255) / 256;

    if (ws_size < o || N > SLAB) {
        // dense fallback (precompute only, then R3 kernel)
        hipMemsetAsync(d_out, 0, (size_t)out_size * sizeof(float), stream);
        k_pre<<<dim3(nPre), dim3(256), 0, stream>>>(
            positions, log_scales, rotations, weights, points,
            params, aux, pcnt, N, M, nPre);
        int nPer = (N + NSPLIT - 1) / NSPLIT;
        dim3 grid((M + 256 * COARSEN - 1) / (256 * COARSEN), NSPLIT);
        gbf_eval_dense<<<grid, dim3(256), 0, stream>>>(points, (const float4*)params, out, M, N, nPer);
        return;
    }

    hipMemsetAsync(pcnt, 0, NSC * 2 * 4, stream);   // pcnt + pfill

    k_pre<<<dim3(nPre + NHB), dim3(256), 0, stream>>>(
        positions, log_scales, rotations, weights, points,
        params, aux, pcnt, N, M, nPre);

    k_lists<<<dim3(NSC + 1), dim3(256), 0, stream>>>(
        (const float4*)aux, pcnt, pstart, lcnt, lists, N);

    k_scatter<<<dim3(nHist), dim3(256), 0, stream>>>(
        points, pstart, pfill, sortedPts, M);

    k_eval<<<dim3(NSC, ECH), dim3(EVB), 0, stream>>>(
        sortedPts, (const float4*)params, pcnt, pstart, lcnt, lists, out);
}

// Round 7
// 39.901 us; speedup vs baseline: 2.5613x; 1.0760x over previous
//
#include <hip/hip_runtime.h>
#include <math.h>

// ---------------- tunables ----------------
#define SCc     8            // supercells per dim
#define NSC     512          // 8^3
#define SCW     32.0f        // supercell width
#define SLAB    2048         // Gaussian-list capacity per cell (= max N for sparse path)
#define LLEN    256          // staged list chunk (LDS = LLEN*48B = 12 KB)
#define EVB     128          // eval block threads
#define ECH     2            // point-chunk blocks per cell
#define NHB     64           // histogram / scatter blocks (M/NHB points each)
#define QCUT    22.0f        // drop when d2 > QCUT*lambda_max (term <= 0.1*e^-11)

typedef float v2f __attribute__((ext_vector_type(2)));
static __device__ __forceinline__ v2f s2(float s) { v2f r; r.x = s; r.y = s; return r; }
static __device__ __forceinline__ v2f pkfma(v2f a, v2f b, v2f c) {
    return __builtin_elementwise_fma(a, b, c);
}
static __device__ __forceinline__ float fexp2(float x) {
#if __has_builtin(__builtin_amdgcn_exp2f)
    return __builtin_amdgcn_exp2f(x);
#else
    return exp2f(x);
#endif
}

static __device__ __forceinline__ int scell_of(float x, float y, float z) {
    int cx = min(SCc - 1, max(0, (int)(x * (1.0f / SCW))));
    int cy = min(SCc - 1, max(0, (int)(y * (1.0f / SCW))));
    int cz = min(SCc - 1, max(0, (int)(z * (1.0f / SCW))));
    return (cz << 6) | (cy << 3) | cx;
}

static __device__ __forceinline__ float cell_d2(int c, float mx, float my, float mz) {
    float lx = (c & 7) * SCW,        hx = lx + SCW;
    float ly = ((c >> 3) & 7) * SCW, hy = ly + SCW;
    float lz = (c >> 6) * SCW,       hz = lz + SCW;
    float dx = fmaxf(fmaxf(lx - mx, mx - hx), 0.0f);
    float dy = fmaxf(fmaxf(ly - my, my - hy), 0.0f);
    float dz = fmaxf(fmaxf(lz - mz, mz - hz), 0.0f);
    return dx * dx + dy * dy + dz * dz;
}

// ---------------- K1: per-Gaussian precompute; partial point histograms ----------------
// No buffer needs pre-zeroing: histogram blocks write their full partial row
// with plain stores.
__global__ __launch_bounds__(256) void k_pre(
    const float* __restrict__ positions,
    const float* __restrict__ log_scales,
    const float* __restrict__ rotations,
    const float* __restrict__ weights,
    const float* __restrict__ points,
    float* __restrict__ params,      // N x 12
    float* __restrict__ aux,         // N x 4: ux,uy,uz,r2
    unsigned* __restrict__ hist_part,// NHB x NSC
    int N, int M, int nPre)
{
    if ((int)blockIdx.x < nPre) {
        int i = blockIdx.x * 256 + threadIdx.x;
        if (i >= N) return;

        float s0 = expf(log_scales[3*i+0]);
        float s1 = expf(log_scales[3*i+1]);
        float s2_ = expf(log_scales[3*i+2]);
        float v0 = s0*s0, v1 = s1*s1, v2 = s2_*s2_;

        float qw = rotations[4*i+0], qx = rotations[4*i+1];
        float qy = rotations[4*i+2], qz = rotations[4*i+3];
        float nrm = sqrtf(qw*qw + qx*qx + qy*qy + qz*qz) + 1e-8f;
        float inv = 1.0f / nrm;
        qw *= inv; qx *= inv; qy *= inv; qz *= inv;

        float r00 = 1.f - 2.f*(qy*qy + qz*qz);
        float r01 = 2.f*(qx*qy - qz*qw);
        float r02 = 2.f*(qx*qz + qy*qw);
        float r10 = 2.f*(qx*qy + qz*qw);
        float r11 = 1.f - 2.f*(qx*qx + qz*qz);
        float r12 = 2.f*(qy*qz - qx*qw);
        float r20 = 2.f*(qx*qz - qy*qw);
        float r21 = 2.f*(qy*qz + qx*qw);
        float r22 = 1.f - 2.f*(qx*qx + qy*qy);

        float a = r00*r00*v0 + r01*r01*v1 + r02*r02*v2 + 1e-6f;
        float b = r00*r10*v0 + r01*r11*v1 + r02*r12*v2;
        float c = r00*r20*v0 + r01*r21*v1 + r02*r22*v2;
        float d = r10*r10*v0 + r11*r11*v1 + r12*r12*v2 + 1e-6f;
        float e = r10*r20*v0 + r11*r21*v1 + r12*r22*v2;
        float f = r20*r20*v0 + r21*r21*v1 + r22*r22*v2 + 1e-6f;

        float m00 = d*f - e*e;
        float m01 = c*e - b*f;
        float m02 = b*e - c*d;
        float det = a*m00 + b*m01 + c*m02;
        float id  = 1.0f / det;
        float A00 = m00*id, A01 = m01*id, A02 = m02*id;
        float A11 = (a*f - c*c)*id;
        float A12 = (c*b - a*e)*id;
        float A22 = (a*d - b*b)*id;

        float ux = positions[3*i+0], uy = positions[3*i+1], uz = positions[3*i+2];
        float bx = A00*ux + A01*uy + A02*uz;
        float by = A01*ux + A11*uy + A12*uz;
        float bz = A02*ux + A12*uy + A22*uz;
        float cq = ux*bx + uy*by + uz*bz;

        const float kk = -0.72134752044448170368f; // -0.5 * log2(e)
        float* P = params + 12*i;
        P[0]  = kk*A00;      P[1]  = kk*A11;      P[2]  = kk*A22;      P[3] = 2.f*kk*A01;
        P[4]  = 2.f*kk*A02;  P[5]  = 2.f*kk*A12;  P[6]  = -2.f*kk*bx;  P[7] = -2.f*kk*by;
        P[8]  = -2.f*kk*bz;  P[9]  = kk*cq;       P[10] = weights[i];  P[11] = 0.f;

        float L = fmaxf(fmaxf(a + fabsf(b) + fabsf(c),
                              fabsf(b) + d + fabsf(e)),
                        fabsf(c) + fabsf(e) + f);
        aux[4*i+0] = ux; aux[4*i+1] = uy; aux[4*i+2] = uz; aux[4*i+3] = QCUT * L;
    } else {
        __shared__ unsigned hist[NSC];
        int tid = threadIdx.x;
        for (int b = tid; b < NSC; b += 256) hist[b] = 0u;
        __syncthreads();
        int h = (int)blockIdx.x - nPre;
        int mh = (M + NHB - 1) / NHB;
        int m0 = h * mh, m1 = min(M, m0 + mh);
        for (int m = m0 + tid; m < m1; m += 256) {
            int c = scell_of(points[3*m+0], points[3*m+1], points[3*m+2]);
            atomicAdd(&hist[c], 1u);
        }
        __syncthreads();
        for (int b = tid; b < NSC; b += 256) hist_part[h * NSC + b] = hist[b];
    }
}

// ---------------- K2: blocks 0..NSC-1 build per-cell Gaussian lists (ballot-ordered,
// deterministic); block NSC: sum partials -> pcnt, scan -> pstart, bases -> pbase ----------------
__global__ __launch_bounds__(256) void k_lists(
    const float4* __restrict__ aux4,
    const unsigned* __restrict__ hist_part,
    unsigned* __restrict__ pcnt, unsigned* __restrict__ pstart,
    unsigned* __restrict__ pbase,               // NHB x NSC
    unsigned* __restrict__ lcnt, unsigned* __restrict__ lists, int N)
{
    if (blockIdx.x == NSC) {
        __shared__ unsigned sh[256];
        int t = threadIdx.x;
        int c0 = 2*t, c1 = 2*t + 1;
        unsigned s0 = 0, s1 = 0;
        for (int h = 0; h < NHB; ++h) {
            s0 += hist_part[h * NSC + c0];
            s1 += hist_part[h * NSC + c1];
        }
        pcnt[c0] = s0; pcnt[c1] = s1;
        unsigned s = s0 + s1;
        sh[t] = s;
        __syncthreads();
        for (int d = 1; d < 256; d <<= 1) {
            unsigned add = (t >= d) ? sh[t - d] : 0u;
            __syncthreads();
            sh[t] += add;
            __syncthreads();
        }
        unsigned ex = sh[t] - s;
        pstart[c0] = ex; pstart[c1] = ex + s0;
        unsigned run0 = ex, run1 = ex + s0;
        for (int h = 0; h < NHB; ++h) {
            pbase[h * NSC + c0] = run0;  run0 += hist_part[h * NSC + c0];
            pbase[h * NSC + c1] = run1;  run1 += hist_part[h * NSC + c1];
        }
        return;
    }
    int c    = blockIdx.x;
    int lane = threadIdx.x & 63;
    int w    = threadIdx.x >> 6;            // 4 waves, each owns a 512-chunk of N
    unsigned long long lt = (1ULL << lane) - 1ULL;
    int gbase = w * 512;

    unsigned cnt = 0;
    for (int it = 0; it < 8; ++it) {
        int g = gbase + it*64 + lane;
        bool keep = false;
        if (g < N) { float4 a = aux4[g]; keep = cell_d2(c, a.x, a.y, a.z) <= a.w; }
        cnt += (unsigned)__popcll(__ballot(keep));
    }
    __shared__ unsigned wc[4];
    if (lane == 0) wc[w] = cnt;
    __syncthreads();
    unsigned pos = 0;
#pragma unroll
    for (int i = 0; i < 4; ++i) pos += (i < w) ? wc[i] : 0u;
    unsigned total = wc[0] + wc[1] + wc[2] + wc[3];
    unsigned* slab = lists + (size_t)c * SLAB;
    for (int it = 0; it < 8; ++it) {
        int g = gbase + it*64 + lane;
        bool keep = false;
        if (g < N) { float4 a = aux4[g]; keep = cell_d2(c, a.x, a.y, a.z) <= a.w; }
        unsigned long long mask = __ballot(keep);
        if (keep) slab[pos + (unsigned)__popcll(mask & lt)] = (unsigned)g;
        pos += (unsigned)__popcll(mask);
    }
    if (threadIdx.x == 0) lcnt[c] = total;
}

// ---------------- K3: scatter points using per-block bases (no global atomics) ----------------
__global__ __launch_bounds__(256) void k_scatter(
    const float* __restrict__ points, const unsigned* __restrict__ pbase,
    float4* __restrict__ sortedPts, int M)
{
    __shared__ unsigned cur[NSC];
    int tid = threadIdx.x;
    int h = (int)blockIdx.x;
    for (int b = tid; b < NSC; b += 256) cur[b] = pbase[h * NSC + b];
    __syncthreads();
    int mh = (M + NHB - 1) / NHB;
    int m0 = h * mh, m1 = min(M, m0 + mh);
    for (int m = m0 + tid; m < m1; m += 256) {
        float x = points[3*m+0], y = points[3*m+1], z = points[3*m+2];
        int c = scell_of(x, y, z);
        unsigned r = atomicAdd(&cur[c], 1u);   // LDS cursor; order within cell
        float4 sp;                             // doesn't affect out[m]
        sp.x = x; sp.y = y; sp.z = z; sp.w = __uint_as_float((unsigned)m);
        sortedPts[r] = sp;
    }
}

// ---------------- K4: eval — LDS-staged list, atomic-free single-write output ----------------
__global__ __launch_bounds__(EVB) void k_eval(
    const float4* __restrict__ sortedPts, const float4* __restrict__ P4,
    const unsigned* __restrict__ pcnt, const unsigned* __restrict__ pstart,
    const unsigned* __restrict__ lcnt, const unsigned* __restrict__ lists,
    float* __restrict__ out)
{
    __shared__ float4 sl[LLEN * 3];
    int c    = blockIdx.x;
    int tid  = threadIdx.x;
    int npts = (int)pcnt[c];
    unsigned ps = pstart[c];
    int len  = (int)lcnt[c];
    const unsigned* lst = lists + (size_t)c * SLAB;

    for (int pb = (int)blockIdx.y * EVB; pb < npts; pb += ECH * EVB) {
        int pi = pb + tid;
        bool act = pi < npts;
        float4 p = sortedPts[ps + (act ? pi : 0)];
        float x = p.x, yv = p.y, zv = p.z;
        float xx = x*x, yy = yv*yv, zz = zv*zv;
        float xy = x*yv, xz = x*zv, yz = yv*zv;
        float acc = 0.f;

        for (int k0 = 0; k0 < len; k0 += LLEN) {
            int kn = min(LLEN, len - k0);
            __syncthreads();
            for (int e = tid; e < kn; e += EVB) {
                int g = (int)lst[k0 + e];
                sl[3*e + 0] = P4[3*g + 0];
                sl[3*e + 1] = P4[3*g + 1];
                sl[3*e + 2] = P4[3*g + 2];
            }
            __syncthreads();
#pragma unroll 2
            for (int e = 0; e < kn; ++e) {
                float4 q0 = sl[3*e + 0];   // Q00,Q11,Q22,Q01
                float4 q1 = sl[3*e + 1];   // Q02,Q12,Lx,Ly
                float4 q2 = sl[3*e + 2];   // Lz,C,W,pad

                float t0 = fmaf(q0.x, xx, q2.y);
                t0 = fmaf(q0.w, xy, t0);
                t0 = fmaf(q1.z, x,  t0);
                float t1 = q0.y * yy;
                t1 = fmaf(q1.y, yz, t1);
                t1 = fmaf(q1.w, yv, t1);
                float t2 = q0.z * zz;
                t2 = fmaf(q1.x, xz, t2);
                t2 = fmaf(q2.x, zv, t2);
                float e2 = (t0 + t1) + t2;
                acc = fmaf(q2.z, fexp2(e2), acc);
            }
        }
        if (act) out[__float_as_uint(p.w)] = acc;   // written exactly once
    }
}

// ---------------- dense fallback (R3 kernel; not used when ws suffices) ----------------
#define NSPLIT 32
#define COARSEN 4
__global__ __launch_bounds__(256, 8) void gbf_eval_dense(
    const float* __restrict__ points,
    const float4* __restrict__ params,
    float* __restrict__ out, int M, int N, int nPer)
{
    int p0 = blockIdx.x * (256 * COARSEN) + threadIdx.x;
    int p1 = p0 + 256, p2 = p0 + 512, p3 = p0 + 768;
    int c0 = min(p0, M-1), c1 = min(p1, M-1), c2 = min(p2, M-1), c3 = min(p3, M-1);

    v2f X1, Y1, Z1, X2_, Y2_, Z2_;
    X1.x = points[3*c0+0]; X1.y = points[3*c1+0];
    Y1.x = points[3*c0+1]; Y1.y = points[3*c1+1];
    Z1.x = points[3*c0+2]; Z1.y = points[3*c1+2];
    X2_.x = points[3*c2+0]; X2_.y = points[3*c3+0];
    Y2_.x = points[3*c2+1]; Y2_.y = points[3*c3+1];
    Z2_.x = points[3*c2+2]; Z2_.y = points[3*c3+2];

    v2f XX1 = X1*X1, YY1 = Y1*Y1, ZZ1 = Z1*Z1;
    v2f XY1 = X1*Y1, XZ1 = X1*Z1, YZ1 = Y1*Z1;
    v2f XX2 = X2_*X2_, YY2 = Y2_*Y2_, ZZ2 = Z2_*Z2_;
    v2f XY2 = X2_*Y2_, XZ2 = X2_*Z2_, YZ2 = Y2_*Z2_;

    int jbase = blockIdx.y * nPer;
    int jend = min(nPer, N - jbase);
    int base = jbase * 3;
    v2f acc1; acc1.x = 0.f; acc1.y = 0.f;
    v2f acc2 = acc1;

#pragma unroll 2
    for (int j = 0; j < jend; ++j) {
        float4 q0 = params[base + 3*j + 0];
        float4 q1 = params[base + 3*j + 1];
        float4 q2 = params[base + 3*j + 2];

        v2f t0 = pkfma(s2(q0.x), XX1, s2(q2.y));
        t0 = pkfma(s2(q0.w), XY1, t0);
        t0 = pkfma(s2(q1.z), X1,  t0);
        v2f t1 = s2(q0.y) * YY1;
        t1 = pkfma(s2(q1.y), YZ1, t1);
        t1 = pkfma(s2(q1.w), Y1,  t1);
        v2f t2 = s2(q0.z) * ZZ1;
        t2 = pkfma(s2(q1.x), XZ1, t2);
        t2 = pkfma(s2(q2.x), Z1,  t2);
        v2f e1 = (t0 + t1) + t2;

        v2f u0 = pkfma(s2(q0.x), XX2, s2(q2.y));
        u0 = pkfma(s2(q0.w), XY2, u0);
        u0 = pkfma(s2(q1.z), X2_, u0);
        v2f u1 = s2(q0.y) * YY2;
        u1 = pkfma(s2(q1.y), YZ2, u1);
        u1 = pkfma(s2(q1.w), Y2_, u1);
        v2f u2 = s2(q0.z) * ZZ2;
        u2 = pkfma(s2(q1.x), XZ2, u2);
        u2 = pkfma(s2(q2.x), Z2_, u2);
        v2f e2 = (u0 + u1) + u2;

        v2f g1, g2;
        g1.x = fexp2(e1.x); g1.y = fexp2(e1.y);
        g2.x = fexp2(e2.x); g2.y = fexp2(e2.y);
        acc1 = pkfma(s2(q2.z), g1, acc1);
        acc2 = pkfma(s2(q2.z), g2, acc2);
    }
    if (p0 < M) atomicAdd(&out[p0], acc1.x);
    if (p1 < M) atomicAdd(&out[p1], acc1.y);
    if (p2 < M) atomicAdd(&out[p2], acc2.x);
    if (p3 < M) atomicAdd(&out[p3], acc2.y);
}

// ---------------- host ----------------
extern "C" void kernel_launch(void* const* d_in, const int* in_sizes, int n_in,
                              void* d_out, int out_size, void* d_ws, size_t ws_size,
                              hipStream_t stream)
{
    const float* points     = (const float*)d_in[0];
    const float* positions  = (const float*)d_in[1];
    const float* log_scales = (const float*)d_in[2];
    const float* rotations  = (const float*)d_in[3];
    const float* weights    = (const float*)d_in[4];
    int M = in_sizes[0] / 3;
    int N = in_sizes[4];
    float* out = (float*)d_out;

    // workspace layout
    char* w = (char*)d_ws;
    size_t o = 0;
    float*    params    = (float*)(w + o);    o += (size_t)N * 12 * 4;
    float*    aux       = (float*)(w + o);    o += (size_t)N * 4 * 4;
    unsigned* hist_part = (unsigned*)(w + o); o += (size_t)NHB * NSC * 4;
    unsigned* pbase     = (unsigned*)(w + o); o += (size_t)NHB * NSC * 4;
    unsigned* pcnt      = (unsigned*)(w + o); o += NSC * 4;
    unsigned* pstart    = (unsigned*)(w + o); o += NSC * 4;
    unsigned* lcnt      = (unsigned*)(w + o); o += NSC * 4;
    unsigned* lists     = (unsigned*)(w + o); o += (size_t)NSC * SLAB * 4;
    float4*   sortedPts = (float4*)(w + o);   o += (size_t)M * 16;

    int nPre = (N + 255) / 256;

    if (ws_size < o || N > SLAB) {
        // dense fallback (precompute only, then R3 kernel)
        hipMemsetAsync(d_out, 0, (size_t)out_size * sizeof(float), stream);
        k_pre<<<dim3(nPre), dim3(256), 0, stream>>>(
            positions, log_scales, rotations, weights, points,
            params, aux, hist_part, N, M, nPre);
        int nPer = (N + NSPLIT - 1) / NSPLIT;
        dim3 grid((M + 256 * COARSEN - 1) / (256 * COARSEN), NSPLIT);
        gbf_eval_dense<<<grid, dim3(256), 0, stream>>>(points, (const float4*)params, out, M, N, nPer);
        return;
    }

    k_pre<<<dim3(nPre + NHB), dim3(256), 0, stream>>>(
        positions, log_scales, rotations, weights, points,
        params, aux, hist_part, N, M, nPre);

    k_lists<<<dim3(NSC + 1), dim3(256), 0, stream>>>(
        (const float4*)aux, hist_part, pcnt, pstart, pbase, lcnt, lists, N);

    k_scatter<<<dim3(NHB), dim3(256), 0, stream>>>(
        points, pbase, sortedPts, M);

    k_eval<<<dim3(NSC, ECH), dim3(EVB), 0, stream>>>(
        sortedPts, (const float4*)params, pcnt, pstart, lcnt, lists, out);
}